// Round 1
// baseline (32.175 us; speedup 1.0000x reference)
//
#include <hip/hip_runtime.h>
#include <math.h>

// Problem constants: x[B=32][N=2048][K=8], W[N][C=32][J=16][K=8], R[N][C]
// out[b][c][j] = squash_j( sum_n softmax_n(R)[n,c] * sum_k W[n,c,j,k]*x[b,n,k] )

#define NN 2048
#define CC 32
#define JJ 16
#define KK 8
#define BB 32

// ---------------- Kernel A: column softmax over n, per c ----------------
__global__ void caps_softmax(const float* __restrict__ R, float* __restrict__ Rn) {
  const int c = blockIdx.x;   // 0..31
  const int t = threadIdx.x;  // 0..255
  __shared__ float col[NN];
  __shared__ float red[256];

  float m = -INFINITY;
  for (int n = t; n < NN; n += 256) {
    float v = R[(size_t)n * CC + c];
    col[n] = v;
    m = fmaxf(m, v);
  }
  red[t] = m;
  __syncthreads();
  for (int h = 128; h >= 1; h >>= 1) {
    if (t < h) red[t] = fmaxf(red[t], red[t + h]);
    __syncthreads();
  }
  m = red[0];
  __syncthreads();

  float ssum = 0.f;
  for (int n = t; n < NN; n += 256) {
    float e = expf(col[n] - m);
    col[n] = e;
    ssum += e;
  }
  red[t] = ssum;
  __syncthreads();
  for (int h = 128; h >= 1; h >>= 1) {
    if (t < h) red[t] += red[t + h];
    __syncthreads();
  }
  float inv = 1.0f / red[0];
  for (int n = t; n < NN; n += 256) {
    Rn[(size_t)n * CC + c] = col[n] * inv;
  }
}

// ---------------- async global->LDS helper (16B per lane) ----------------
__device__ __forceinline__ void g2l16(const float* g, float* l) {
  __builtin_amdgcn_global_load_lds((const __attribute__((address_space(1))) void*)g,
                                   (__attribute__((address_space(3))) void*)l, 16, 0, 0);
}

// ---------------- Kernel B: main streaming contraction ----------------
// grid 256 = 64 n-chunks x 4 c-groups; block 512 = 8 waves.
// wave ws: within each 8-n slab, handles n_loc = ws.
// lane: j = lane&15 (output dim), bo = lane>>4 (batch quad); b_reg = 8 (b = bo*8+bi)
// acc[bi][ci] for ci in c-group of 8.
// LDS (dynamic 80KB): ldsW[2][8192] dwords, ldsX[2][2048] dwords.
//   W slab layout (per n): linear c-slice of 1024 dwords, granule-swizzled q^=((q>>3)&1)
//   x slab layout (per n): [bi(8)][bo(4)][k(8)]  (b = bo*8+bi)
__global__ void __launch_bounds__(512) caps_main(const float* __restrict__ x,
                                                 const float* __restrict__ W,
                                                 const float* __restrict__ Rn,
                                                 float* __restrict__ P) {
  const int bid = blockIdx.x;
  const int cg = bid & 3;        // c-group 0..3 (8 c each)
  const int chunk = bid >> 2;    // 0..63 (32 n each)
  const int n0 = chunk * 32;
  const int tid = threadIdx.x;
  const int ws = tid >> 6;
  const int lane = tid & 63;
  const int j = lane & 15;
  const int bo = lane >> 4;

  extern __shared__ float smem[];
  float* ldsW = smem;           // [2][8192]
  float* ldsX = smem + 16384;   // [2][2048]

  float acc[8][8];
#pragma unroll
  for (int a = 0; a < 8; ++a)
#pragma unroll
    for (int b = 0; b < 8; ++b) acc[a][b] = 0.f;

  // x staging decode for this thread (granule = tid): [nl][bi][bo2][h]
  const int xs_nl = tid >> 6;
  const int xs_bi = (tid >> 3) & 7;
  const int xs_bo = (tid >> 1) & 3;
  const int xs_h  = tid & 1;
  const int xs_b  = xs_bo * 8 + xs_bi;

  // ---- prologue: stage slab 0 into buffer 0 ----
  {
    const int sbase = n0;
#pragma unroll
    for (int it = 0; it < 4; ++it) {
      int G = it * 512 + tid;
      int nl = G >> 8, q = G & 255;
      int qs = q ^ ((q >> 3) & 1);
      g2l16(W + (size_t)(sbase + nl) * 4096 + cg * 1024 + qs * 4,
            ldsW + (size_t)(it * 512 + ws * 64) * 4);
    }
    g2l16(x + (size_t)xs_b * (NN * KK) + (size_t)(sbase + xs_nl) * KK + xs_h * 4,
          ldsX + (size_t)ws * 256);
  }
  __syncthreads();

  const int xw = (j >> 2) & 1;              // swizzle bit for W reads
  const int jo_lo = j * 8 + xw * 4;         // k 0..3 granule
  const int jo_hi = j * 8 + (xw ^ 1) * 4;   // k 4..7 granule

  for (int s = 0; s < 4; ++s) {
    const int cur = s & 1;
    if (s < 3) {
      const int nxt = cur ^ 1;
      const int sbase = n0 + (s + 1) * 8;
#pragma unroll
      for (int it = 0; it < 4; ++it) {
        int G = it * 512 + tid;
        int nl = G >> 8, q = G & 255;
        int qs = q ^ ((q >> 3) & 1);
        g2l16(W + (size_t)(sbase + nl) * 4096 + cg * 1024 + qs * 4,
              ldsW + (size_t)nxt * 8192 + (size_t)(it * 512 + ws * 64) * 4);
      }
      g2l16(x + (size_t)xs_b * (NN * KK) + (size_t)(sbase + xs_nl) * KK + xs_h * 4,
            ldsX + (size_t)nxt * 2048 + (size_t)ws * 256);
    }
    // ---- compute current slab: this wave's n ----
    {
      const int nglob = n0 + s * 8 + ws;
      const float* Xb = ldsX + (size_t)cur * 2048 + (size_t)ws * 256;
      const float* Wb = ldsW + (size_t)cur * 8192 + (size_t)ws * 1024;

      float xa[8][8];
#pragma unroll
      for (int bi = 0; bi < 8; ++bi) {
        float4 lo = *(const float4*)(Xb + bi * 32 + bo * 8);
        float4 hi = *(const float4*)(Xb + bi * 32 + bo * 8 + 4);
        xa[bi][0] = lo.x; xa[bi][1] = lo.y; xa[bi][2] = lo.z; xa[bi][3] = lo.w;
        xa[bi][4] = hi.x; xa[bi][5] = hi.y; xa[bi][6] = hi.z; xa[bi][7] = hi.w;
      }
      const float* rrow = Rn + (size_t)nglob * CC + cg * 8;
#pragma unroll
      for (int ci = 0; ci < 8; ++ci) {
        float4 wa = *(const float4*)(Wb + ci * 128 + jo_lo);
        float4 wb = *(const float4*)(Wb + ci * 128 + jo_hi);
        float rv = rrow[ci];
        float w0 = wa.x * rv, w1 = wa.y * rv, w2 = wa.z * rv, w3 = wa.w * rv;
        float w4 = wb.x * rv, w5 = wb.y * rv, w6 = wb.z * rv, w7 = wb.w * rv;
#pragma unroll
        for (int bi = 0; bi < 8; ++bi) {
          float a = acc[bi][ci];
          a = fmaf(w0, xa[bi][0], a);
          a = fmaf(w1, xa[bi][1], a);
          a = fmaf(w2, xa[bi][2], a);
          a = fmaf(w3, xa[bi][3], a);
          a = fmaf(w4, xa[bi][4], a);
          a = fmaf(w5, xa[bi][5], a);
          a = fmaf(w6, xa[bi][6], a);
          a = fmaf(w7, xa[bi][7], a);
          acc[bi][ci] = a;
        }
      }
    }
    __syncthreads();
  }

  // ---- cross-wave tree reduction (reuse ldsW region: 4 regions x 4096) ----
  float* red = smem;
#pragma unroll
  for (int half = 4; half >= 1; half >>= 1) {
    if (ws >= half && ws < 2 * half) {
      float* dst = red + (size_t)(ws - half) * 4096;
#pragma unroll
      for (int bi = 0; bi < 8; ++bi)
#pragma unroll
        for (int ci = 0; ci < 8; ++ci)
          dst[(bi * 8 + ci) * 64 + lane] = acc[bi][ci];
    }
    __syncthreads();
    if (ws < half) {
      const float* srcp = red + (size_t)ws * 4096;
#pragma unroll
      for (int bi = 0; bi < 8; ++bi)
#pragma unroll
        for (int ci = 0; ci < 8; ++ci)
          acc[bi][ci] += srcp[(bi * 8 + ci) * 64 + lane];
    }
    __syncthreads();
  }

  // wave 0 writes this block's partial: P[bid][idx=bi*8+ci][lane]
  if (ws == 0) {
    float* dst = P + (size_t)bid * 4096;
#pragma unroll
    for (int bi = 0; bi < 8; ++bi)
#pragma unroll
      for (int ci = 0; ci < 8; ++ci)
        dst[(bi * 8 + ci) * 64 + lane] = acc[bi][ci];
  }
}

// ---------------- Kernel C: cross-chunk reduce + squash ----------------
__global__ void caps_reduce(const float* __restrict__ P, float* __restrict__ out) {
  const int g = blockIdx.x * 256 + threadIdx.x;  // 0..16383 = b*512 + c*16 + j
  const int j = g & 15;
  const int c = (g >> 4) & 31;
  const int b = g >> 9;
  const int bo = b >> 3, bi = b & 7;
  const int cgi = c >> 3, ci = c & 7;
  const int idx = (bi * 8 + ci) * 64 + (bo * 16 + j);

  float s = 0.f;
  for (int chunk = 0; chunk < 64; ++chunk) {
    s += P[(size_t)(chunk * 4 + cgi) * 4096 + idx];
  }
  // ||s||^2 over j within 16-lane group
  float sq = s * s;
  sq += __shfl_xor(sq, 8, 16);
  sq += __shfl_xor(sq, 4, 16);
  sq += __shfl_xor(sq, 2, 16);
  sq += __shfl_xor(sq, 1, 16);
  float ss = sq + 1e-7f;
  float scale = sqrtf(ss) / (1.0f + ss);
  out[g] = scale * s;
}

extern "C" void kernel_launch(void* const* d_in, const int* in_sizes, int n_in,
                              void* d_out, int out_size, void* d_ws, size_t ws_size,
                              hipStream_t stream) {
  const float* x = (const float*)d_in[0];   // 32*2048*8
  const float* W = (const float*)d_in[1];   // 2048*32*16*8
  const float* R = (const float*)d_in[2];   // 2048*32
  float* out = (float*)d_out;               // 32*32*16

  float* Rn = (float*)d_ws;                 // 65536 floats
  float* P  = (float*)d_ws + 65536;         // 256*4096 floats (4 MB)

  // allow 80KB dynamic LDS (gfx950 has 160KB/CU)
  hipFuncSetAttribute((const void*)caps_main,
                      hipFuncAttributeMaxDynamicSharedMemorySize, 81920);

  caps_softmax<<<32, 256, 0, stream>>>(R, Rn);
  caps_main<<<256, 512, 81920, stream>>>(x, W, Rn, P);
  caps_reduce<<<64, 256, 0, stream>>>(P, out);
}